// Round 8
// baseline (560.159 us; speedup 1.0000x reference)
//
#include <hip/hip_runtime.h>

// MultiHeadLinearAttention (B=8,S=4096,IN=1024,H=16,D=64). ALL I/O fp32.
//   k = x@wk + bk ; K = elu(k)+1 ; v = x@wv + bv
//   KV[b,c] = sum_s K*v (elementwise), Ksum[b,c] = sum_s K
//   out[b,s,:] = gelu_tanh((KV_b/Ksum_b)@wo + bo) — s-independent broadcast.
// v10: B operands moved OUT of LDS into registers (global->reg, L2-resident
//   2MiB/matrix, prefetched 1 tile ahead, P/Q double set, 2-unrolled loop).
//   LDS keeps only A (v7-verified staging: depth-3 counted gload_lds,
//   swizzle u'=u^((row>>1)&3), 0 conflicts). LDS read traffic/tile drops
//   96KB -> 32KB; MFMA pipe (1242 cyc/tile/CU) becomes dominant resource.
//   B-reg consumption is compiler-scoreboarded (no manual vmcnt exposure);
//   manual counted waits cover only A staging: steady vmcnt(12) =
//   {B(t+1) 8 + A(t+3) 2 + A(t+2) 2} allowed outstanding, in-order drain
//   forces A(t+1)+B(t) complete. Tail: vmcnt(10) @29, vmcnt(8) @30.

#define SEQ   4096
#define MROWS 32768
#define KDIM  1024
#define HD    1024

typedef __bf16 bf16x8 __attribute__((ext_vector_type(8)));
typedef float floatx4 __attribute__((ext_vector_type(4)));

__device__ __forceinline__ unsigned short f2bf(float f) {
    unsigned int u = __float_as_uint(f);
    u += 0x7fffu + ((u >> 16) & 1u);   // RNE
    return (unsigned short)(u >> 16);
}
__device__ __forceinline__ void cvt8(const float* __restrict__ p, unsigned short* d) {
    const float4 a = *(const float4*)p;
    const float4 b = *(const float4*)(p + 4);
    d[0] = f2bf(a.x); d[1] = f2bf(a.y); d[2] = f2bf(a.z); d[3] = f2bf(a.w);
    d[4] = f2bf(b.x); d[5] = f2bf(b.y); d[6] = f2bf(b.z); d[7] = f2bf(b.w);
}

typedef const __attribute__((address_space(1))) unsigned int* gas_t;
typedef __attribute__((address_space(3))) unsigned int* las_t;
__device__ __forceinline__ void async16(const void* g, void* l) {
    // one global_load_lds_dwordx4: LDS dst = readfirstlane(l) + lane*16
    __builtin_amdgcn_global_load_lds((gas_t)g, (las_t)l, 16, 0, 0);
}

// ---------- Prepass (merged): cvt_x (blocks 0..16383) + transpose_w --------
__global__ __launch_bounds__(256)
void prep(const float* __restrict__ x, unsigned short* __restrict__ xb,
          const float* __restrict__ wk, const float* __restrict__ wv,
          unsigned short* __restrict__ wkT, unsigned short* __restrict__ wvT)
{
    __shared__ alignas(16) unsigned short Ts[64][72];
    const int t = threadIdx.x;
    if (blockIdx.x < 16384) {
        const size_t p = ((size_t)blockIdx.x * 256 + t) * 8;
        union { uint4 u; unsigned short s[8]; } o;
        cvt8(x + p, o.s);
        *(uint4*)(xb + p) = o.u;
        return;
    }
    const int bid = blockIdx.x - 16384;          // 0..511
    const float* W = (bid >> 8) ? wv : wk;
    unsigned short* WT = (bid >> 8) ? wvT : wkT;
    const int k0 = (bid & 15) * 64, n0 = ((bid >> 4) & 15) * 64;
    const int r4 = (t >> 4) * 4, c4 = (t & 15) * 4;
#pragma unroll
    for (int i = 0; i < 4; i++) {
        const float4 f = *(const float4*)(W + (size_t)(k0 + r4 + i) * HD + n0 + c4);
        Ts[c4 + 0][r4 + i] = f2bf(f.x);
        Ts[c4 + 1][r4 + i] = f2bf(f.y);
        Ts[c4 + 2][r4 + i] = f2bf(f.z);
        Ts[c4 + 3][r4 + i] = f2bf(f.w);
    }
    __syncthreads();
    const int rr = t >> 3, cc = (t & 7) * 8;
#pragma unroll
    for (int h = 0; h < 2; h++)
        *(uint4*)(WT + (size_t)(n0 + rr + h * 32) * KDIM + k0 + cc) =
            *(const uint4*)&Ts[rr + h * 32][cc];
}

// ---------- Kernel 1 (fast): 16x16x32 dual-B GEMM, B in registers ----------
// grid 1024 x 512 thr. BM=256, BN=128 each for K and V. BK=32. 8 waves 4m x 2n.
// LDS: As[4] x 16 KiB (A only). A: v7 staging + swizzle. B: global->reg
// prefetch (P/Q sets), 8 dwordx4 per wave per tile from L2-hot wkT/wvT.
__global__ __launch_bounds__(512, 1)
void kv_gemm_fast(const unsigned short* __restrict__ xb,
                  const unsigned short* __restrict__ wkT,
                  const unsigned short* __restrict__ wvT,
                  const float* __restrict__ bk, const float* __restrict__ bv,
                  float2* __restrict__ KVZ)
{
    __shared__ alignas(16) unsigned short As[4][256 * 32];   // 64 KiB total

    const int t = threadIdx.x;

    // T1 bijective XCD decode: 1024 = 8 XCDs x (16 mtiles x 8 ntiles).
    const int id = blockIdx.x;
    const int xcd = id & 7, o = id >> 3;
    const int mtile = xcd * 16 + (o >> 3);   // 0..127
    const int ntile = o & 7;                 // 0..7
    const int m0 = mtile * 256;
    const int n0 = ntile * 128;
    const int b  = m0 >> 12;

    const int w = t >> 6, lane = t & 63;
    const int wm = w >> 1, wn = w & 1;       // 4m x 2n
    const int lrow = lane & 15, quad = lane >> 4;

    // conflict-free A read swizzle (v7-verified): u' = quad ^ ((row>>1)&3)
    const int usw = quad ^ ((lrow >> 1) & 3);

    // A staging (v7-verified): call j covers 16B unit g=j*512+t
    const int srow  = t >> 2;                        // 0..127
    const int usrc  = (t & 3) ^ ((t >> 3) & 3);
    const unsigned short* gA0 = xb + (size_t)(m0 + srow) * KDIM + usrc * 8;
    const unsigned short* gA1 = gA0 + (size_t)128 * KDIM;

    // B bases: lane reads col (wn*64 + ni*16 + lrow), k-bytes [quad*16 +
    // tile*64, +16). Lanes {lrow, +16, +32, +48} cover one contiguous 64B line.
    const unsigned short* gBk = wkT + (size_t)(n0 + wn * 64 + lrow) * KDIM + quad * 8;
    const unsigned short* gBv = wvT + (size_t)(n0 + wn * 64 + lrow) * KDIM + quad * 8;

#define STAGE_A(c, tk) do {                                                   \
        const int ko_ = (tk) * 32;                                            \
        async16(gA0 + ko_, &As[c][ t        * 8]);                            \
        async16(gA1 + ko_, &As[c][(512 + t) * 8]);                            \
    } while (0)

    // B fragment sets (static names — rule #20). 8 loads each.
    bf16x8 PK[4], PV[4], QK[4], QV[4];

#define LOADB(K_, V_, tk) do {                                                \
        _Pragma("unroll")                                                     \
        for (int ni = 0; ni < 4; ++ni) {                                      \
            K_[ni] = *(const bf16x8*)(gBk + ni * 16 * KDIM + (tk) * 32);      \
            V_[ni] = *(const bf16x8*)(gBv + ni * 16 * KDIM + (tk) * 32);      \
        }                                                                     \
    } while (0)

#define TILE_BODY(tk, CK, CV, NK, NV, DOLB, DOST, NWAIT) do {                 \
        const unsigned short* A_ = As[(tk) & 3];                              \
        bf16x8 af[4];                                                         \
        _Pragma("unroll")                                                     \
        for (int mi = 0; mi < 4; ++mi)                                        \
            af[mi] = *(const bf16x8*)&A_[(wm * 64 + mi * 16 + lrow) * 32 + usw * 8]; \
        if (DOLB) LOADB(NK, NV, (tk) + 1);                                    \
        if (DOST) STAGE_A(((tk) + 3) & 3, (tk) + 3);                          \
        __builtin_amdgcn_s_setprio(1);                                        \
        _Pragma("unroll")                                                     \
        for (int mi = 0; mi < 4; ++mi)                                        \
            _Pragma("unroll")                                                 \
            for (int ni = 0; ni < 4; ++ni) {                                  \
                accK[mi][ni] = __builtin_amdgcn_mfma_f32_16x16x32_bf16(       \
                    af[mi], CK[ni], accK[mi][ni], 0, 0, 0);                   \
                accV[mi][ni] = __builtin_amdgcn_mfma_f32_16x16x32_bf16(       \
                    af[mi], CV[ni], accV[mi][ni], 0, 0, 0);                   \
            }                                                                 \
        __builtin_amdgcn_s_setprio(0);                                        \
        if (NWAIT == 12) asm volatile("s_waitcnt vmcnt(12)" ::: "memory");    \
        else if (NWAIT == 10) asm volatile("s_waitcnt vmcnt(10)" ::: "memory");\
        else if (NWAIT == 8)  asm volatile("s_waitcnt vmcnt(8)"  ::: "memory");\
        if (NWAIT >= 0) __builtin_amdgcn_s_barrier();                         \
    } while (0)

    floatx4 accK[4][4], accV[4][4];
#pragma unroll
    for (int i = 0; i < 4; i++)
#pragma unroll
        for (int j = 0; j < 4; j++) {
            accK[i][j] = (floatx4){0.f, 0.f, 0.f, 0.f};
            accV[i][j] = (floatx4){0.f, 0.f, 0.f, 0.f};
        }

    // prologue: A tiles 0..2 staged (6 ops), B(0) -> P (8 ops).
    // vmcnt(12): A(0)'s 2 ops (oldest) forced done; A1,A2,B0 may stay in
    // flight (compiler scoreboard waits B0 before first MFMA use).
    STAGE_A(0, 0);
    STAGE_A(1, 1);
    STAGE_A(2, 2);
    LOADB(PK, PV, 0);
    asm volatile("s_waitcnt vmcnt(12)" ::: "memory");
    __builtin_amdgcn_s_barrier();

    // main: tiles 0..27 (even: consume P load Q, odd: consume Q load P).
    // steady vmcnt(12) = {B(t+1) 8, A(t+3) 2, A(t+2) 2} allowed outstanding
    // -> A(t+1), B(t) and older complete before the barrier.
    for (int it = 0; it < 14; ++it) {
        const int tk = it * 2;
        TILE_BODY(tk,     PK, PV, QK, QV, 1, 1, 12);
        TILE_BODY(tk + 1, QK, QV, PK, PV, 1, 1, 12);
    }
    // tail: t=28 (stage 31, vmcnt12), t=29 (vmcnt10: {B(30)8,A(31)2}),
    // t=30 (vmcnt8: {B(31)8}; A(31) forced done), t=31 (no wait/barrier).
    TILE_BODY(28, PK, PV, QK, QV, 1, 1, 12);
    TILE_BODY(29, QK, QV, PK, PV, 1, 0, 10);
    TILE_BODY(30, PK, PV, QK, QV, 1, 0, 8);
    TILE_BODY(31, QK, QV, PK, PV, 0, 0, -1);

#undef STAGE_A
#undef LOADB
#undef TILE_BODY

    // Epilogue (verified): 16x16 C/D col = lane&15, rows = quad*4+r.
#pragma unroll
    for (int ni = 0; ni < 4; ++ni) {
        const int colw = n0 + wn * 64 + ni * 16 + lrow;
        const float bkf = bk[colw];
        const float bvf = bv[colw];
        float pKV = 0.f, pK = 0.f;
#pragma unroll
        for (int mi = 0; mi < 4; ++mi) {
#pragma unroll
            for (int r = 0; r < 4; ++r) {
                const float kk = accK[mi][ni][r] + bkf;
                const float K  = (kk > 0.f) ? (kk + 1.f) : __expf(kk);
                const float vv = accV[mi][ni][r] + bvf;
                pKV += K * vv;
                pK  += K;
            }
        }
        pKV += __shfl_xor(pKV, 16, 64);
        pKV += __shfl_xor(pKV, 32, 64);
        pK  += __shfl_xor(pK, 16, 64);
        pK  += __shfl_xor(pK, 32, 64);
        if (quad == 0) {
            atomicAdd(&KVZ[b * HD + colw].x, pKV);
            atomicAdd(&KVZ[b * HD + colw].y, pK);
        }
    }
}

// ---------- Kernel 1 (fallback, verified): fp32 staging ----------
__global__ __launch_bounds__(256)
void kv_gemm(const float* __restrict__ x,
             const float* __restrict__ wk, const float* __restrict__ bk,
             const float* __restrict__ wv, const float* __restrict__ bv,
             float2* __restrict__ KVZ)
{
    __shared__ alignas(16) unsigned short As [128][40];
    __shared__ alignas(16) unsigned short BsK[128][40];
    __shared__ alignas(16) unsigned short BsV[128][40];

    const int t = threadIdx.x;
    const int n0 = blockIdx.x * 128;
    const int m0 = blockIdx.y * 128;
    const int b  = m0 >> 12;

    const int wave = t >> 6, lane = t & 63;
    const int wm = wave >> 1, wn = wave & 1;
    const int lrow = lane & 15, quad = lane >> 4;

    floatx4 accK[4][4], accV[4][4];
#pragma unroll
    for (int i = 0; i < 4; i++)
#pragma unroll
        for (int j = 0; j < 4; j++) {
            accK[i][j] = (floatx4){0.f, 0.f, 0.f, 0.f};
            accV[i][j] = (floatx4){0.f, 0.f, 0.f, 0.f};
        }

    const int arow0 = t >> 2, akc = (t & 3) * 8;
    const int bk0 = t >> 4, bnc = (t & 15) * 8;

    for (int k0 = 0; k0 < KDIM; k0 += 32) {
        __syncthreads();
        {
            union { uint4 u; unsigned short s[8]; } ua, ub;
            cvt8(x + (size_t)(m0 + arow0) * KDIM + k0 + akc, ua.s);
            cvt8(x + (size_t)(m0 + arow0 + 64) * KDIM + k0 + akc, ub.s);
            *(uint4*)&As[arow0][akc] = ua.u;
            *(uint4*)&As[arow0 + 64][akc] = ub.u;
        }
        {
            unsigned short k0s[8], k1s[8], v0s[8], v1s[8];
            cvt8(wk + (size_t)(k0 + bk0) * HD + n0 + bnc, k0s);
            cvt8(wk + (size_t)(k0 + bk0 + 16) * HD + n0 + bnc, k1s);
            cvt8(wv + (size_t)(k0 + bk0) * HD + n0 + bnc, v0s);
            cvt8(wv + (size_t)(k0 + bk0 + 16) * HD + n0 + bnc, v1s);
#pragma unroll
            for (int j = 0; j < 8; j++) {
                BsK[bnc + j][bk0]      = k0s[j];
                BsK[bnc + j][bk0 + 16] = k1s[j];
                BsV[bnc + j][bk0]      = v0s[j];
                BsV[bnc + j][bk0 + 16] = v1s[j];
            }
        }
        __syncthreads();

        bf16x8 af[4], bfK[4], bfV[4];
#pragma unroll
        for (int mi = 0; mi < 4; mi++)
            af[mi] = *(const bf16x8*)&As[wm * 64 + mi * 16 + lrow][quad * 8];
#pragma unroll
        for (int ni = 0; ni < 4; ni++) {
            bfK[ni] = *(const bf16x8*)&BsK[wn * 64 + ni * 16 + lrow][quad * 8];
            bfV[ni] = *(const bf16x8*)&BsV[wn * 64 + ni * 16 + lrow][quad * 8];
        }
#pragma unroll
        for (int mi = 0; mi < 4; mi++)
#pragma unroll
            for (int ni = 0; ni < 4; ni++) {
                accK[mi][ni] = __builtin_amdgcn_mfma_f32_16x16x32_bf16(
                    af[mi], bfK[ni], accK[mi][ni], 0, 0, 0);
                accV[mi][ni] = __builtin_amdgcn_mfma_f32_16x16x32_bf16(
                    af[mi], bfV[ni], accV[mi][ni], 0, 0, 0);
            }
    }

#pragma unroll
    for (int ni = 0; ni < 4; ni++) {
        const int colw = n0 + wn * 64 + ni * 16 + lrow;
        const float bkf = bk[colw];
        const float bvf = bv[colw];
        float pKV = 0.f, pK = 0.f;
#pragma unroll
        for (int mi = 0; mi < 4; mi++) {
#pragma unroll
            for (int r = 0; r < 4; r++) {
                const float kk = accK[mi][ni][r] + bkf;
                const float K  = (kk > 0.f) ? (kk + 1.f) : __expf(kk);
                const float vv = accV[mi][ni][r] + bvf;
                pKV += K * vv;
                pK  += K;
            }
        }
        pKV += __shfl_xor(pKV, 16, 64);
        pKV += __shfl_xor(pKV, 32, 64);
        pK  += __shfl_xor(pK, 16, 64);
        pK  += __shfl_xor(pK, 32, 64);
        if (quad == 0) {
            atomicAdd(&KVZ[b * HD + colw].x, pKV);
            atomicAdd(&KVZ[b * HD + colw].y, pK);
        }
    }
}

// ---------- Kernel 2 (fused): gelu((KV/Ksum)@wo + bo) broadcast to out -----
__global__ __launch_bounds__(256)
void rowgemm_bcast(const float2* __restrict__ KVZ,
                   const float* __restrict__ wo, const float* __restrict__ bo,
                   float* __restrict__ out)
{
    __shared__ float a[1024];
    __shared__ float red[4][64];
    __shared__ float sval[64];
    const int t = threadIdx.x;
    const int b = blockIdx.x;
    const int o0 = blockIdx.y * 64;
    const int s0 = blockIdx.z * 512;

    for (int c = t; c < 1024; c += 256) {
        const float2 z = KVZ[b * HD + c];
        a[c] = z.x / z.y;
    }
    __syncthreads();

    const int cs = t >> 6, oi = t & 63;
    float p = 0.f;
    const int cbeg = cs * 256;
    for (int c = cbeg; c < cbeg + 256; ++c)
        p += a[c] * wo[(size_t)c * HD + o0 + oi];
    red[cs][oi] = p;
    __syncthreads();

    if (t < 64) {
        float v = red[0][t] + red[1][t] + red[2][t] + red[3][t] + bo[o0 + t];
        sval[t] = 0.5f * v *
            (1.f + tanhf(0.7978845608028654f * (v + 0.044715f * v * v * v)));
    }
    __syncthreads();

    const float4 sv4 = *(const float4*)&sval[(t & 15) * 4];
    for (int r = t >> 4; r < 512; r += 16)
        *(float4*)&out[((size_t)(b * SEQ + s0 + r)) * HD + o0 + (t & 15) * 4] = sv4;
}

// ---------- Fallback epilogue kernels ----------
__global__ __launch_bounds__(256)
void rowgemm(const float2* __restrict__ KVZ,
             const float* __restrict__ wo, const float* __restrict__ bo,
             float* __restrict__ rowf)
{
    __shared__ float a[1024];
    __shared__ float red[4][64];
    const int t = threadIdx.x;
    const int b = blockIdx.x;
    const int o0 = blockIdx.y * 64;

    for (int c = t; c < 1024; c += 256) {
        const float2 z = KVZ[b * HD + c];
        a[c] = z.x / z.y;
    }
    __syncthreads();

    const int cs = t >> 6, oi = t & 63;
    float p = 0.f;
    const int cbeg = cs * 256;
    for (int c = cbeg; c < cbeg + 256; ++c)
        p += a[c] * wo[(size_t)c * HD + o0 + oi];
    red[cs][oi] = p;
    __syncthreads();

    if (t < 64) {
        float v = red[0][t] + red[1][t] + red[2][t] + red[3][t] + bo[o0 + t];
        const float g = 0.5f * v *
            (1.f + tanhf(0.7978845608028654f * (v + 0.044715f * v * v * v)));
        rowf[b * HD + o0 + t] = g;
    }
}

__global__ __launch_bounds__(256)
void broadcast_rows(const float* __restrict__ rowf, float* __restrict__ out)
{
    const size_t idx = (size_t)blockIdx.x * 256 + threadIdx.x;
    const size_t p = idx * 4;
    const int row = (int)(p >> 10);
    const int b = row >> 12;
    const int col = (int)(p & 1023);
    *(float4*)(out + p) = *(const float4*)(rowf + b * HD + col);
}

extern "C" void kernel_launch(void* const* d_in, const int* in_sizes, int n_in,
                              void* d_out, int out_size, void* d_ws, size_t ws_size,
                              hipStream_t stream)
{
    const float* x  = (const float*)d_in[0];
    const float* wk = (const float*)d_in[3];
    const float* bk = (const float*)d_in[4];
    const float* wv = (const float*)d_in[5];
    const float* bv = (const float*)d_in[6];
    const float* wo = (const float*)d_in[7];
    const float* bo = (const float*)d_in[8];
    float* out = (float*)d_out;

    const size_t NEED = (size_t)72 * 1024 * 1024;
    if (ws_size >= NEED) {
        unsigned short* xb  = (unsigned short*)d_ws;                       // 64 MiB
        unsigned short* wkT = (unsigned short*)((char*)d_ws + (67u << 20));// 2 MiB
        unsigned short* wvT = (unsigned short*)((char*)d_ws + (69u << 20));// 2 MiB
        float2* KVZ = (float2*)((char*)d_ws + (71u << 20));                // 64 KiB

        hipMemsetAsync(KVZ, 0, 8 * HD * sizeof(float2), stream);
        prep<<<dim3(16384 + 512), 256, 0, stream>>>(x, xb, wk, wv, wkT, wvT);
        kv_gemm_fast<<<dim3(1024), 512, 0, stream>>>(xb, wkT, wvT, bk, bv, KVZ);
        rowgemm_bcast<<<dim3(8, 16, 8), 256, 0, stream>>>(KVZ, wo, bo, out);
    } else {
        float2* KVZ = (float2*)d_ws;
        float* rowf = (float*)((char*)d_ws + 65536);
        hipMemsetAsync(KVZ, 0, 8 * HD * sizeof(float2), stream);
        kv_gemm<<<dim3(8, 256), 256, 0, stream>>>(x, wk, bk, wv, bv, KVZ);
        rowgemm<<<dim3(8, 16), 256, 0, stream>>>(KVZ, wo, bo, rowf);
        broadcast_rows<<<dim3((MROWS * HD / 4) / 256), 256, 0, stream>>>(rowf, out);
    }
}

// Round 9
// 400.002 us; speedup vs baseline: 1.4004x; 1.4004x over previous
//
#include <hip/hip_runtime.h>

// MultiHeadLinearAttention (B=8,S=4096,IN=1024,H=16,D=64). ALL I/O fp32.
//   k = x@wk + bk ; K = elu(k)+1 ; v = x@wv + bv
//   KV[b,c] = sum_s K*v (elementwise), Ksum[b,c] = sum_s K
//   out[b,s,:] = gelu_tanh((KV_b/Ksum_b)@wo + bo) — s-independent broadcast.
// v11 (consolidation): v7 GEMM verbatim (measured 144.5us, 0 bank conflicts,
//   MfmaUtil 42%) + merged prep (cvt_x + transpose_w + KVZ zeroing in one
//   launch) + fused rowgemm_bcast. Findings from v8/v9/v10 experiments:
//   - dual K/V acc (128 AGPR) is forced by the fused epilogue (K*v needs both
//     in-thread) -> ~224 unified regs -> 2 waves/SIMD, 1 block/CU, hard cap.
//   - at that occupancy LDS reads (1156cyc) + MFMA (1242cyc) + barrier
//     serialize per tile = 2709cyc measured: v7 IS this structure's floor.
//   - manual counted-vmcnt (gload_lds staging) and compiler-scoreboarded
//     register loads CANNOT coexist (v10: compiler emits vmcnt(0) per tile).

#define SEQ   4096
#define MROWS 32768
#define KDIM  1024
#define HD    1024
#define T32   32          // K-tiles of 32

typedef __bf16 bf16x8 __attribute__((ext_vector_type(8)));
typedef float floatx4 __attribute__((ext_vector_type(4)));

__device__ __forceinline__ unsigned short f2bf(float f) {
    unsigned int u = __float_as_uint(f);
    u += 0x7fffu + ((u >> 16) & 1u);   // RNE
    return (unsigned short)(u >> 16);
}
__device__ __forceinline__ void cvt8(const float* __restrict__ p, unsigned short* d) {
    const float4 a = *(const float4*)p;
    const float4 b = *(const float4*)(p + 4);
    d[0] = f2bf(a.x); d[1] = f2bf(a.y); d[2] = f2bf(a.z); d[3] = f2bf(a.w);
    d[4] = f2bf(b.x); d[5] = f2bf(b.y); d[6] = f2bf(b.z); d[7] = f2bf(b.w);
}

typedef const __attribute__((address_space(1))) unsigned int* gas_t;
typedef __attribute__((address_space(3))) unsigned int* las_t;
__device__ __forceinline__ void async16(const void* g, void* l) {
    // one global_load_lds_dwordx4: LDS dst = readfirstlane(l) + lane*16
    __builtin_amdgcn_global_load_lds((gas_t)g, (las_t)l, 16, 0, 0);
}

// ---------- Prepass (merged): cvt_x + transpose_w + KVZ zero ----------
__global__ __launch_bounds__(256)
void prep(const float* __restrict__ x, unsigned short* __restrict__ xb,
          const float* __restrict__ wk, const float* __restrict__ wv,
          unsigned short* __restrict__ wkT, unsigned short* __restrict__ wvT,
          float4* __restrict__ KVZ4)
{
    __shared__ alignas(16) unsigned short Ts[64][72];
    const int t = threadIdx.x;
    if (blockIdx.x < 16384) {
        const size_t p = ((size_t)blockIdx.x * 256 + t) * 8;
        union { uint4 u; unsigned short s[8]; } o;
        cvt8(x + p, o.s);
        *(uint4*)(xb + p) = o.u;
        return;
    }
    if (blockIdx.x >= 16384 + 512) {                 // KVZ zero: 4096 float4
#pragma unroll
        for (int i = 0; i < 16; ++i)
            KVZ4[t * 16 + i] = (float4){0.f, 0.f, 0.f, 0.f};
        return;
    }
    const int bid = blockIdx.x - 16384;              // 0..511
    const float* W = (bid >> 8) ? wv : wk;
    unsigned short* WT = (bid >> 8) ? wvT : wkT;
    const int k0 = (bid & 15) * 64, n0 = ((bid >> 4) & 15) * 64;
    const int r4 = (t >> 4) * 4, c4 = (t & 15) * 4;
#pragma unroll
    for (int i = 0; i < 4; i++) {
        const float4 f = *(const float4*)(W + (size_t)(k0 + r4 + i) * HD + n0 + c4);
        Ts[c4 + 0][r4 + i] = f2bf(f.x);
        Ts[c4 + 1][r4 + i] = f2bf(f.y);
        Ts[c4 + 2][r4 + i] = f2bf(f.z);
        Ts[c4 + 3][r4 + i] = f2bf(f.w);
    }
    __syncthreads();
    const int rr = t >> 3, cc = (t & 7) * 8;
#pragma unroll
    for (int h = 0; h < 2; h++)
        *(uint4*)(WT + (size_t)(n0 + rr + h * 32) * KDIM + k0 + cc) =
            *(const uint4*)&Ts[rr + h * 32][cc];
}

// ---------- Kernel 1 (v7 verbatim): 16x16x32 dual-B GEMM, 4-deep pipeline --
// grid 1024 x 512 thr. BM=256 rows, BN=128 cols for BOTH K and V. BK=32.
// 8 waves as 4m x 2n; wave tile 64m x 64n per matrix; acc 4x4x2 x f32x4.
// LDS: As[4]/Bs[4] 16 KiB each = 128 KiB. Layout [row][32] (64B rows),
// swizzle u' = u ^ ((row>>1)&3) on 16B units (pre-swizzled gload source +
// swizzled ds_read). 4 async16/STAGE -> counted vmcnt multiples of 4.
// One barrier per tile; prefetch depth 3.
__global__ __launch_bounds__(512, 1)
void kv_gemm_fast(const unsigned short* __restrict__ xb,
                  const unsigned short* __restrict__ wkT,
                  const unsigned short* __restrict__ wvT,
                  const float* __restrict__ bk, const float* __restrict__ bv,
                  float2* __restrict__ KVZ)
{
    __shared__ alignas(16) unsigned short As[4][256 * 32];   // 4 x 16 KiB
    __shared__ alignas(16) unsigned short Bs[4][256 * 32];   // 4 x 16 KiB

    const int t = threadIdx.x;

    // T1 bijective XCD decode: 1024 = 8 XCDs x (16 mtiles x 8 ntiles).
    const int id = blockIdx.x;
    const int xcd = id & 7, o = id >> 3;
    const int mtile = xcd * 16 + (o >> 3);   // 0..127
    const int ntile = o & 7;                 // 0..7
    const int m0 = mtile * 256;
    const int n0 = ntile * 128;
    const int b  = m0 >> 12;

    const int w = t >> 6, lane = t & 63;
    const int wm = w >> 1, wn = w & 1;       // 4m x 2n
    const int lrow = lane & 15, quad = lane >> 4;

    // conflict-free read swizzle: u' = quad ^ ((row>>1)&3)
    const int usw = quad ^ ((lrow >> 1) & 3);

    // staging: call j covers 16B unit g=j*512+t: row=g>>2, u=g&3.
    const int srow  = t >> 2;                        // 0..127
    const int usrc  = (t & 3) ^ ((t >> 3) & 3);
    const unsigned short* gA0 = xb  + (size_t)(m0 + srow) * KDIM + usrc * 8;
    const unsigned short* gA1 = gA0 + (size_t)128 * KDIM;
    const unsigned short* gBk = wkT + (size_t)(n0 + srow) * KDIM + usrc * 8;
    const unsigned short* gBv = wvT + (size_t)(n0 + srow) * KDIM + usrc * 8;

#define STAGE(c, tk) do {                                                     \
        const int ko_ = (tk) * 32;                                            \
        async16(gA0 + ko_, &As[c][(0 * 512 + t) * 8]);                        \
        async16(gA1 + ko_, &As[c][(1 * 512 + t) * 8]);                        \
        async16(gBk + ko_, &Bs[c][(0 * 512 + t) * 8]);                        \
        async16(gBv + ko_, &Bs[c][(1 * 512 + t) * 8]);                        \
    } while (0)

    STAGE(0, 0);
    STAGE(1, 1);
    STAGE(2, 2);

    floatx4 accK[4][4], accV[4][4];
#pragma unroll
    for (int i = 0; i < 4; i++)
#pragma unroll
        for (int j = 0; j < 4; j++) {
            accK[i][j] = (floatx4){0.f, 0.f, 0.f, 0.f};
            accV[i][j] = (floatx4){0.f, 0.f, 0.f, 0.f};
        }

    asm volatile("s_waitcnt vmcnt(8)" ::: "memory");   // tile 0 landed
    __builtin_amdgcn_s_barrier();

    for (int tk = 0; tk < T32; ++tk) {
        const unsigned short* A = As[tk & 3];
        const unsigned short* B = Bs[tk & 3];

        bf16x8 af[4], bK[4], bV[4];
#pragma unroll
        for (int mi = 0; mi < 4; ++mi)
            af[mi] = *(const bf16x8*)&A[(wm * 64 + mi * 16 + lrow) * 32 + usw * 8];
#pragma unroll
        for (int ni = 0; ni < 4; ++ni) {
            const int br = wn * 64 + ni * 16 + lrow;
            bK[ni] = *(const bf16x8*)&B[ br        * 32 + usw * 8];
            bV[ni] = *(const bf16x8*)&B[(br + 128) * 32 + usw * 8];
        }

        __builtin_amdgcn_s_setprio(1);
#pragma unroll
        for (int mi = 0; mi < 4; ++mi)
#pragma unroll
            for (int ni = 0; ni < 4; ++ni) {
                accK[mi][ni] = __builtin_amdgcn_mfma_f32_16x16x32_bf16(
                    af[mi], bK[ni], accK[mi][ni], 0, 0, 0);
                accV[mi][ni] = __builtin_amdgcn_mfma_f32_16x16x32_bf16(
                    af[mi], bV[ni], accV[mi][ni], 0, 0, 0);
            }
        __builtin_amdgcn_s_setprio(0);

        // boundary: stage tile tk+3 into buffer (tk-1)&3 (dead for 2 barriers)
        // then make sure tile tk+1 has landed, one barrier, go.
        if (tk + 3 < T32) {
            STAGE((tk + 3) & 3, tk + 3);
            asm volatile("s_waitcnt vmcnt(8)" ::: "memory");  // t+2,t+3 in flight
        } else if (tk == T32 - 3) {
            asm volatile("s_waitcnt vmcnt(4)" ::: "memory");  // only t+2 in flight
        } else if (tk == T32 - 2) {
            asm volatile("s_waitcnt vmcnt(0)" ::: "memory");  // last tile landed
        }
        __builtin_amdgcn_s_barrier();
    }
#undef STAGE

    // Epilogue (verified): 16x16 C/D col = lane&15, rows = quad*4+r.
    // Sum regs over mi,r; shfl_xor 16+32 across quads; quad==0 atomics.
#pragma unroll
    for (int ni = 0; ni < 4; ++ni) {
        const int colw = n0 + wn * 64 + ni * 16 + lrow;
        const float bkf = bk[colw];
        const float bvf = bv[colw];
        float pKV = 0.f, pK = 0.f;
#pragma unroll
        for (int mi = 0; mi < 4; ++mi) {
#pragma unroll
            for (int r = 0; r < 4; ++r) {
                const float kk = accK[mi][ni][r] + bkf;
                const float K  = (kk > 0.f) ? (kk + 1.f) : __expf(kk);
                const float vv = accV[mi][ni][r] + bvf;
                pKV += K * vv;
                pK  += K;
            }
        }
        pKV += __shfl_xor(pKV, 16, 64);
        pKV += __shfl_xor(pKV, 32, 64);
        pK  += __shfl_xor(pK, 16, 64);
        pK  += __shfl_xor(pK, 32, 64);
        if (quad == 0) {
            atomicAdd(&KVZ[b * HD + colw].x, pKV);
            atomicAdd(&KVZ[b * HD + colw].y, pK);
        }
    }
}

// ---------- Kernel 1 (fallback, verified): fp32 staging ----------
__global__ __launch_bounds__(256)
void kv_gemm(const float* __restrict__ x,
             const float* __restrict__ wk, const float* __restrict__ bk,
             const float* __restrict__ wv, const float* __restrict__ bv,
             float2* __restrict__ KVZ)
{
    __shared__ alignas(16) unsigned short As [128][40];
    __shared__ alignas(16) unsigned short BsK[128][40];
    __shared__ alignas(16) unsigned short BsV[128][40];

    const int t = threadIdx.x;
    const int n0 = blockIdx.x * 128;
    const int m0 = blockIdx.y * 128;
    const int b  = m0 >> 12;

    const int wave = t >> 6, lane = t & 63;
    const int wm = wave >> 1, wn = wave & 1;
    const int lrow = lane & 15, quad = lane >> 4;

    floatx4 accK[4][4], accV[4][4];
#pragma unroll
    for (int i = 0; i < 4; i++)
#pragma unroll
        for (int j = 0; j < 4; j++) {
            accK[i][j] = (floatx4){0.f, 0.f, 0.f, 0.f};
            accV[i][j] = (floatx4){0.f, 0.f, 0.f, 0.f};
        }

    const int arow0 = t >> 2, akc = (t & 3) * 8;
    const int bk0 = t >> 4, bnc = (t & 15) * 8;

    for (int k0 = 0; k0 < KDIM; k0 += 32) {
        __syncthreads();
        {
            union { uint4 u; unsigned short s[8]; } ua, ub;
            cvt8(x + (size_t)(m0 + arow0) * KDIM + k0 + akc, ua.s);
            cvt8(x + (size_t)(m0 + arow0 + 64) * KDIM + k0 + akc, ub.s);
            *(uint4*)&As[arow0][akc] = ua.u;
            *(uint4*)&As[arow0 + 64][akc] = ub.u;
        }
        {
            unsigned short k0s[8], k1s[8], v0s[8], v1s[8];
            cvt8(wk + (size_t)(k0 + bk0) * HD + n0 + bnc, k0s);
            cvt8(wk + (size_t)(k0 + bk0 + 16) * HD + n0 + bnc, k1s);
            cvt8(wv + (size_t)(k0 + bk0) * HD + n0 + bnc, v0s);
            cvt8(wv + (size_t)(k0 + bk0 + 16) * HD + n0 + bnc, v1s);
#pragma unroll
            for (int j = 0; j < 8; j++) {
                BsK[bnc + j][bk0]      = k0s[j];
                BsK[bnc + j][bk0 + 16] = k1s[j];
                BsV[bnc + j][bk0]      = v0s[j];
                BsV[bnc + j][bk0 + 16] = v1s[j];
            }
        }
        __syncthreads();

        bf16x8 af[4], bfK[4], bfV[4];
#pragma unroll
        for (int mi = 0; mi < 4; mi++)
            af[mi] = *(const bf16x8*)&As[wm * 64 + mi * 16 + lrow][quad * 8];
#pragma unroll
        for (int ni = 0; ni < 4; ni++) {
            bfK[ni] = *(const bf16x8*)&BsK[wn * 64 + ni * 16 + lrow][quad * 8];
            bfV[ni] = *(const bf16x8*)&BsV[wn * 64 + ni * 16 + lrow][quad * 8];
        }
#pragma unroll
        for (int mi = 0; mi < 4; mi++)
#pragma unroll
            for (int ni = 0; ni < 4; ni++) {
                accK[mi][ni] = __builtin_amdgcn_mfma_f32_16x16x32_bf16(
                    af[mi], bfK[ni], accK[mi][ni], 0, 0, 0);
                accV[mi][ni] = __builtin_amdgcn_mfma_f32_16x16x32_bf16(
                    af[mi], bfV[ni], accV[mi][ni], 0, 0, 0);
            }
    }

#pragma unroll
    for (int ni = 0; ni < 4; ni++) {
        const int colw = n0 + wn * 64 + ni * 16 + lrow;
        const float bkf = bk[colw];
        const float bvf = bv[colw];
        float pKV = 0.f, pK = 0.f;
#pragma unroll
        for (int mi = 0; mi < 4; mi++) {
#pragma unroll
            for (int r = 0; r < 4; r++) {
                const float kk = accK[mi][ni][r] + bkf;
                const float K  = (kk > 0.f) ? (kk + 1.f) : __expf(kk);
                const float vv = accV[mi][ni][r] + bvf;
                pKV += K * vv;
                pK  += K;
            }
        }
        pKV += __shfl_xor(pKV, 16, 64);
        pKV += __shfl_xor(pKV, 32, 64);
        pK  += __shfl_xor(pK, 16, 64);
        pK  += __shfl_xor(pK, 32, 64);
        if (quad == 0) {
            atomicAdd(&KVZ[b * HD + colw].x, pKV);
            atomicAdd(&KVZ[b * HD + colw].y, pK);
        }
    }
}

// ---------- Kernel 2 (fused): gelu((KV/Ksum)@wo + bo) broadcast to out -----
__global__ __launch_bounds__(256)
void rowgemm_bcast(const float2* __restrict__ KVZ,
                   const float* __restrict__ wo, const float* __restrict__ bo,
                   float* __restrict__ out)
{
    __shared__ float a[1024];
    __shared__ float red[4][64];
    __shared__ float sval[64];
    const int t = threadIdx.x;
    const int b = blockIdx.x;
    const int o0 = blockIdx.y * 64;
    const int s0 = blockIdx.z * 512;

    for (int c = t; c < 1024; c += 256) {
        const float2 z = KVZ[b * HD + c];
        a[c] = z.x / z.y;
    }
    __syncthreads();

    const int cs = t >> 6, oi = t & 63;
    float p = 0.f;
    const int cbeg = cs * 256;
    for (int c = cbeg; c < cbeg + 256; ++c)
        p += a[c] * wo[(size_t)c * HD + o0 + oi];
    red[cs][oi] = p;
    __syncthreads();

    if (t < 64) {
        float v = red[0][t] + red[1][t] + red[2][t] + red[3][t] + bo[o0 + t];
        sval[t] = 0.5f * v *
            (1.f + tanhf(0.7978845608028654f * (v + 0.044715f * v * v * v)));
    }
    __syncthreads();

    const float4 sv4 = *(const float4*)&sval[(t & 15) * 4];
    for (int r = t >> 4; r < 512; r += 16)
        *(float4*)&out[((size_t)(b * SEQ + s0 + r)) * HD + o0 + (t & 15) * 4] = sv4;
}

// ---------- Fallback epilogue kernels ----------
__global__ __launch_bounds__(256)
void rowgemm(const float2* __restrict__ KVZ,
             const float* __restrict__ wo, const float* __restrict__ bo,
             float* __restrict__ rowf)
{
    __shared__ float a[1024];
    __shared__ float red[4][64];
    const int t = threadIdx.x;
    const int b = blockIdx.x;
    const int o0 = blockIdx.y * 64;

    for (int c = t; c < 1024; c += 256) {
        const float2 z = KVZ[b * HD + c];
        a[c] = z.x / z.y;
    }
    __syncthreads();

    const int cs = t >> 6, oi = t & 63;
    float p = 0.f;
    const int cbeg = cs * 256;
    for (int c = cbeg; c < cbeg + 256; ++c)
        p += a[c] * wo[(size_t)c * HD + o0 + oi];
    red[cs][oi] = p;
    __syncthreads();

    if (t < 64) {
        float v = red[0][t] + red[1][t] + red[2][t] + red[3][t] + bo[o0 + t];
        const float g = 0.5f * v *
            (1.f + tanhf(0.7978845608028654f * (v + 0.044715f * v * v * v)));
        rowf[b * HD + o0 + t] = g;
    }
}

__global__ __launch_bounds__(256)
void broadcast_rows(const float* __restrict__ rowf, float* __restrict__ out)
{
    const size_t idx = (size_t)blockIdx.x * 256 + threadIdx.x;
    const size_t p = idx * 4;
    const int row = (int)(p >> 10);
    const int b = row >> 12;
    const int col = (int)(p & 1023);
    *(float4*)(out + p) = *(const float4*)(rowf + b * HD + col);
}

extern "C" void kernel_launch(void* const* d_in, const int* in_sizes, int n_in,
                              void* d_out, int out_size, void* d_ws, size_t ws_size,
                              hipStream_t stream)
{
    const float* x  = (const float*)d_in[0];
    const float* wk = (const float*)d_in[3];
    const float* bk = (const float*)d_in[4];
    const float* wv = (const float*)d_in[5];
    const float* bv = (const float*)d_in[6];
    const float* wo = (const float*)d_in[7];
    const float* bo = (const float*)d_in[8];
    float* out = (float*)d_out;

    const size_t NEED = (size_t)72 * 1024 * 1024;
    if (ws_size >= NEED) {
        unsigned short* xb  = (unsigned short*)d_ws;                       // 64 MiB
        unsigned short* wkT = (unsigned short*)((char*)d_ws + (67u << 20));// 2 MiB
        unsigned short* wvT = (unsigned short*)((char*)d_ws + (69u << 20));// 2 MiB
        float2* KVZ = (float2*)((char*)d_ws + (71u << 20));                // 64 KiB

        prep<<<dim3(16384 + 512 + 1), 256, 0, stream>>>(x, xb, wk, wv, wkT, wvT,
                                                        (float4*)KVZ);
        kv_gemm_fast<<<dim3(1024), 512, 0, stream>>>(xb, wkT, wvT, bk, bv, KVZ);
        rowgemm_bcast<<<dim3(8, 16, 8), 256, 0, stream>>>(KVZ, wo, bo, out);
    } else {
        float2* KVZ = (float2*)d_ws;
        float* rowf = (float*)((char*)d_ws + 65536);
        hipMemsetAsync(KVZ, 0, 8 * HD * sizeof(float2), stream);
        kv_gemm<<<dim3(8, 256), 256, 0, stream>>>(x, wk, bk, wv, bv, KVZ);
        rowgemm<<<dim3(8, 16), 256, 0, stream>>>(KVZ, wo, bo, rowf);
        broadcast_rows<<<dim3((MROWS * HD / 4) / 256), 256, 0, stream>>>(rowf, out);
    }
}

// Round 10
// 395.723 us; speedup vs baseline: 1.4155x; 1.0108x over previous
//
#include <hip/hip_runtime.h>

// MultiHeadLinearAttention (B=8,S=4096,IN=1024,H=16,D=64). ALL I/O fp32.
//   k = x@wk + bk ; K = elu(k)+1 ; v = x@wv + bv
//   KV[b,c] = sum_s K*v (elementwise), Ksum[b,c] = sum_s K
//   out[b,s,:] = gelu_tanh((KV_b/Ksum_b)@wo + bo) — s-independent broadcast.
// v12 = v11 with the K-loop at m201 phase granularity: 4 phases per 2 K-tiles,
//   each phase {<=8 ds_reads for this phase's 16-MFMA cluster; 2 gload_lds;
//   BAR; setprio 16 MFMA; BAR}; ONE counted vmcnt per 2 tiles (steady
//   vmcnt(8) = {A,B}(t+3),(t+4) outstanding; tail 8/4/0 by enumeration).
//   Same register footprint as v7 (single af/bK/bV set) -> no spill -> manual
//   vmcnt counts remain valid. Buffer safety: stage(t+3)->buf(t-1)&3 (reads
//   closed 2 barriers ago), stage(t+4)->buf t&3 (reads closed at P2 barrier).

#define SEQ   4096
#define MROWS 32768
#define KDIM  1024
#define HD    1024

typedef __bf16 bf16x8 __attribute__((ext_vector_type(8)));
typedef float floatx4 __attribute__((ext_vector_type(4)));

__device__ __forceinline__ unsigned short f2bf(float f) {
    unsigned int u = __float_as_uint(f);
    u += 0x7fffu + ((u >> 16) & 1u);   // RNE
    return (unsigned short)(u >> 16);
}
__device__ __forceinline__ void cvt8(const float* __restrict__ p, unsigned short* d) {
    const float4 a = *(const float4*)p;
    const float4 b = *(const float4*)(p + 4);
    d[0] = f2bf(a.x); d[1] = f2bf(a.y); d[2] = f2bf(a.z); d[3] = f2bf(a.w);
    d[4] = f2bf(b.x); d[5] = f2bf(b.y); d[6] = f2bf(b.z); d[7] = f2bf(b.w);
}

typedef const __attribute__((address_space(1))) unsigned int* gas_t;
typedef __attribute__((address_space(3))) unsigned int* las_t;
__device__ __forceinline__ void async16(const void* g, void* l) {
    // one global_load_lds_dwordx4: LDS dst = readfirstlane(l) + lane*16
    __builtin_amdgcn_global_load_lds((gas_t)g, (las_t)l, 16, 0, 0);
}

// ---------- Prepass (merged): cvt_x + transpose_w + KVZ zero ----------
__global__ __launch_bounds__(256)
void prep(const float* __restrict__ x, unsigned short* __restrict__ xb,
          const float* __restrict__ wk, const float* __restrict__ wv,
          unsigned short* __restrict__ wkT, unsigned short* __restrict__ wvT,
          float4* __restrict__ KVZ4)
{
    __shared__ alignas(16) unsigned short Ts[64][72];
    const int t = threadIdx.x;
    if (blockIdx.x < 16384) {
        const size_t p = ((size_t)blockIdx.x * 256 + t) * 8;
        union { uint4 u; unsigned short s[8]; } o;
        cvt8(x + p, o.s);
        *(uint4*)(xb + p) = o.u;
        return;
    }
    if (blockIdx.x >= 16384 + 512) {                 // KVZ zero: 4096 float4
#pragma unroll
        for (int i = 0; i < 16; ++i)
            KVZ4[t * 16 + i] = (float4){0.f, 0.f, 0.f, 0.f};
        return;
    }
    const int bid = blockIdx.x - 16384;              // 0..511
    const float* W = (bid >> 8) ? wv : wk;
    unsigned short* WT = (bid >> 8) ? wvT : wkT;
    const int k0 = (bid & 15) * 64, n0 = ((bid >> 4) & 15) * 64;
    const int r4 = (t >> 4) * 4, c4 = (t & 15) * 4;
#pragma unroll
    for (int i = 0; i < 4; i++) {
        const float4 f = *(const float4*)(W + (size_t)(k0 + r4 + i) * HD + n0 + c4);
        Ts[c4 + 0][r4 + i] = f2bf(f.x);
        Ts[c4 + 1][r4 + i] = f2bf(f.y);
        Ts[c4 + 2][r4 + i] = f2bf(f.z);
        Ts[c4 + 3][r4 + i] = f2bf(f.w);
    }
    __syncthreads();
    const int rr = t >> 3, cc = (t & 7) * 8;
#pragma unroll
    for (int h = 0; h < 2; h++)
        *(uint4*)(WT + (size_t)(n0 + rr + h * 32) * KDIM + k0 + cc) =
            *(const uint4*)&Ts[rr + h * 32][cc];
}

// ---------- Kernel 1: 16x16x32 dual-B GEMM, 4-phase/2-tile pipeline --------
// grid 1024 x 512 thr. BM=256, BN=128 each for K and V. BK=32. 8 waves 4m x 2n.
// LDS: As[4]/Bs[4] 16 KiB each = 128 KiB, layout [row][32] (64B rows),
// swizzle u' = quad ^ ((row>>1)&3) (pre-swizzled gload source + swizzled
// ds_read; v7-verified, 0 conflicts). Depth-3 prefetch.
__global__ __launch_bounds__(512, 1)
void kv_gemm_fast(const unsigned short* __restrict__ xb,
                  const unsigned short* __restrict__ wkT,
                  const unsigned short* __restrict__ wvT,
                  const float* __restrict__ bk, const float* __restrict__ bv,
                  float2* __restrict__ KVZ)
{
    __shared__ alignas(16) unsigned short As[4][256 * 32];   // 4 x 16 KiB
    __shared__ alignas(16) unsigned short Bs[4][256 * 32];   // 4 x 16 KiB

    const int t = threadIdx.x;

    // T1 bijective XCD decode: 1024 = 8 XCDs x (16 mtiles x 8 ntiles).
    const int id = blockIdx.x;
    const int xcd = id & 7, o = id >> 3;
    const int mtile = xcd * 16 + (o >> 3);   // 0..127
    const int ntile = o & 7;                 // 0..7
    const int m0 = mtile * 256;
    const int n0 = ntile * 128;
    const int b  = m0 >> 12;

    const int w = t >> 6, lane = t & 63;
    const int wm = w >> 1, wn = w & 1;       // 4m x 2n
    const int lrow = lane & 15, quad = lane >> 4;

    const int usw = quad ^ ((lrow >> 1) & 3);

    // staging (v7-verified): call j covers 16B unit g=j*512+t: row=g>>2,u=g&3
    const int srow  = t >> 2;                        // 0..127
    const int usrc  = (t & 3) ^ ((t >> 3) & 3);
    const unsigned short* gA0 = xb  + (size_t)(m0 + srow) * KDIM + usrc * 8;
    const unsigned short* gA1 = gA0 + (size_t)128 * KDIM;
    const unsigned short* gBk = wkT + (size_t)(n0 + srow) * KDIM + usrc * 8;
    const unsigned short* gBv = wvT + (size_t)(n0 + srow) * KDIM + usrc * 8;

#define STAGE_A(c, tk) do {                                                   \
        const int ko_ = (tk) * 32;                                            \
        async16(gA0 + ko_, &As[c][(0 * 512 + t) * 8]);                        \
        async16(gA1 + ko_, &As[c][(1 * 512 + t) * 8]);                        \
    } while (0)
#define STAGE_B(c, tk) do {                                                   \
        const int ko_ = (tk) * 32;                                            \
        async16(gBk + ko_, &Bs[c][(0 * 512 + t) * 8]);                        \
        async16(gBv + ko_, &Bs[c][(1 * 512 + t) * 8]);                        \
    } while (0)
#define READ_AF(Ap_) do { _Pragma("unroll")                                   \
        for (int mi = 0; mi < 4; ++mi)                                        \
            af[mi] = *(const bf16x8*)&Ap_[(wm * 64 + mi * 16 + lrow) * 32 + usw * 8]; \
    } while (0)
#define READ_BK(Bp_) do { _Pragma("unroll")                                   \
        for (int ni = 0; ni < 4; ++ni)                                        \
            bK[ni] = *(const bf16x8*)&Bp_[(wn * 64 + ni * 16 + lrow) * 32 + usw * 8]; \
    } while (0)
#define READ_BV(Bp_) do { _Pragma("unroll")                                   \
        for (int ni = 0; ni < 4; ++ni)                                        \
            bV[ni] = *(const bf16x8*)&Bp_[(128 + wn * 64 + ni * 16 + lrow) * 32 + usw * 8]; \
    } while (0)
#define MFMA_K do { __builtin_amdgcn_s_setprio(1); _Pragma("unroll")          \
        for (int mi = 0; mi < 4; ++mi) _Pragma("unroll")                      \
            for (int ni = 0; ni < 4; ++ni)                                    \
                accK[mi][ni] = __builtin_amdgcn_mfma_f32_16x16x32_bf16(       \
                    af[mi], bK[ni], accK[mi][ni], 0, 0, 0);                   \
        __builtin_amdgcn_s_setprio(0); } while (0)
#define MFMA_V do { __builtin_amdgcn_s_setprio(1); _Pragma("unroll")          \
        for (int mi = 0; mi < 4; ++mi) _Pragma("unroll")                      \
            for (int ni = 0; ni < 4; ++ni)                                    \
                accV[mi][ni] = __builtin_amdgcn_mfma_f32_16x16x32_bf16(       \
                    af[mi], bV[ni], accV[mi][ni], 0, 0, 0);                   \
        __builtin_amdgcn_s_setprio(0); } while (0)
#define BAR   __builtin_amdgcn_s_barrier()
#define VM(n) asm volatile("s_waitcnt vmcnt(" #n ")" ::: "memory")

    // prologue: tiles 0..2 in flight (12 ops); vmcnt(8) -> tile 0 landed.
    STAGE_A(0, 0); STAGE_B(0, 0);
    STAGE_A(1, 1); STAGE_B(1, 1);
    STAGE_A(2, 2); STAGE_B(2, 2);

    floatx4 accK[4][4], accV[4][4];
#pragma unroll
    for (int i = 0; i < 4; i++)
#pragma unroll
        for (int j = 0; j < 4; j++) {
            accK[i][j] = (floatx4){0.f, 0.f, 0.f, 0.f};
            accV[i][j] = (floatx4){0.f, 0.f, 0.f, 0.f};
        }

    VM(8);
    BAR;

    bf16x8 af[4], bK[4], bV[4];

    // main: tiles 0..27, 2 per iteration, 4 phases. One vmcnt per iteration.
    for (int it = 0; it < 14; ++it) {
        const int tk = it * 2;
        const unsigned short* A0 = As[tk & 3];
        const unsigned short* B0 = Bs[tk & 3];
        const unsigned short* A1 = As[(tk + 1) & 3];
        const unsigned short* B1 = Bs[(tk + 1) & 3];

        // P1: tile tk K-half.  stage A(t+3) -> buf (t-1)&3 (dead 2 barriers)
        READ_AF(A0); READ_BK(B0);
        STAGE_A((tk + 3) & 3, tk + 3);
        BAR; MFMA_K; BAR;
        // P2: tile tk V-half (af still live).
        READ_BV(B0);
        STAGE_B((tk + 3) & 3, tk + 3);
        BAR; MFMA_V; BAR;
        // P3: tile tk+1 K-half.  stage (t+4) -> buf t&3 (reads closed @P2 BAR)
        READ_AF(A1); READ_BK(B1);
        STAGE_A((tk + 4) & 3, tk + 4);
        BAR; MFMA_K; BAR;
        // P4: tile tk+1 V-half. vmcnt(8): allow {A,B}(t+3),(t+4); force (t+2).
        READ_BV(B1);
        STAGE_B((tk + 4) & 3, tk + 4);
        VM(8);
        BAR; MFMA_V; BAR;
    }

    // tail iter A: tiles 28,29. Stage only tile 31 (buf 3; last read t=27).
    {
        const unsigned short* A0 = As[0];
        const unsigned short* B0 = Bs[0];
        const unsigned short* A1 = As[1];
        const unsigned short* B1 = Bs[1];
        READ_AF(A0); READ_BK(B0);
        STAGE_A(3, 31);
        BAR; MFMA_K; BAR;
        READ_BV(B0);
        STAGE_B(3, 31);
        VM(8);                      // outstanding {A30,B30,A31,B31}: 29 landed
        BAR; MFMA_V; BAR;
        READ_AF(A1); READ_BK(B1);
        BAR; MFMA_K; BAR;
        READ_BV(B1);
        VM(4);                      // outstanding {A31,B31}: 30 landed
        BAR; MFMA_V; BAR;
    }
    // tail iter B: tiles 30,31. No staging.
    {
        const unsigned short* A0 = As[2];
        const unsigned short* B0 = Bs[2];
        const unsigned short* A1 = As[3];
        const unsigned short* B1 = Bs[3];
        READ_AF(A0); READ_BK(B0);
        BAR; MFMA_K; BAR;
        READ_BV(B0);
        VM(0);                      // tile 31 landed
        BAR; MFMA_V; BAR;
        READ_AF(A1); READ_BK(B1);
        BAR; MFMA_K; BAR;
        READ_BV(B1);
        MFMA_V;                     // last cluster; epilogue doesn't touch LDS
    }

#undef STAGE_A
#undef STAGE_B
#undef READ_AF
#undef READ_BK
#undef READ_BV
#undef MFMA_K
#undef MFMA_V
#undef BAR
#undef VM

    // Epilogue (verified): 16x16 C/D col = lane&15, rows = quad*4+r.
#pragma unroll
    for (int ni = 0; ni < 4; ++ni) {
        const int colw = n0 + wn * 64 + ni * 16 + lrow;
        const float bkf = bk[colw];
        const float bvf = bv[colw];
        float pKV = 0.f, pK = 0.f;
#pragma unroll
        for (int mi = 0; mi < 4; ++mi) {
#pragma unroll
            for (int r = 0; r < 4; ++r) {
                const float kk = accK[mi][ni][r] + bkf;
                const float K  = (kk > 0.f) ? (kk + 1.f) : __expf(kk);
                const float vv = accV[mi][ni][r] + bvf;
                pKV += K * vv;
                pK  += K;
            }
        }
        pKV += __shfl_xor(pKV, 16, 64);
        pKV += __shfl_xor(pKV, 32, 64);
        pK  += __shfl_xor(pK, 16, 64);
        pK  += __shfl_xor(pK, 32, 64);
        if (quad == 0) {
            atomicAdd(&KVZ[b * HD + colw].x, pKV);
            atomicAdd(&KVZ[b * HD + colw].y, pK);
        }
    }
}

// ---------- Kernel 1 (fallback, verified): fp32 staging ----------
__global__ __launch_bounds__(256)
void kv_gemm(const float* __restrict__ x,
             const float* __restrict__ wk, const float* __restrict__ bk,
             const float* __restrict__ wv, const float* __restrict__ bv,
             float2* __restrict__ KVZ)
{
    __shared__ alignas(16) unsigned short As [128][40];
    __shared__ alignas(16) unsigned short BsK[128][40];
    __shared__ alignas(16) unsigned short BsV[128][40];

    const int t = threadIdx.x;
    const int n0 = blockIdx.x * 128;
    const int m0 = blockIdx.y * 128;
    const int b  = m0 >> 12;

    const int wave = t >> 6, lane = t & 63;
    const int wm = wave >> 1, wn = wave & 1;
    const int lrow = lane & 15, quad = lane >> 4;

    floatx4 accK[4][4], accV[4][4];
#pragma unroll
    for (int i = 0; i < 4; i++)
#pragma unroll
        for (int j = 0; j < 4; j++) {
            accK[i][j] = (floatx4){0.f, 0.f, 0.f, 0.f};
            accV[i][j] = (floatx4){0.f, 0.f, 0.f, 0.f};
        }

    const int arow0 = t >> 2, akc = (t & 3) * 8;
    const int bk0 = t >> 4, bnc = (t & 15) * 8;

    for (int k0 = 0; k0 < KDIM; k0 += 32) {
        __syncthreads();
        {
            union { uint4 u; unsigned short s[8]; } ua, ub;
            cvt8(x + (size_t)(m0 + arow0) * KDIM + k0 + akc, ua.s);
            cvt8(x + (size_t)(m0 + arow0 + 64) * KDIM + k0 + akc, ub.s);
            *(uint4*)&As[arow0][akc] = ua.u;
            *(uint4*)&As[arow0 + 64][akc] = ub.u;
        }
        {
            unsigned short k0s[8], k1s[8], v0s[8], v1s[8];
            cvt8(wk + (size_t)(k0 + bk0) * HD + n0 + bnc, k0s);
            cvt8(wk + (size_t)(k0 + bk0 + 16) * HD + n0 + bnc, k1s);
            cvt8(wv + (size_t)(k0 + bk0) * HD + n0 + bnc, v0s);
            cvt8(wv + (size_t)(k0 + bk0 + 16) * HD + n0 + bnc, v1s);
#pragma unroll
            for (int j = 0; j < 8; j++) {
                BsK[bnc + j][bk0]      = k0s[j];
                BsK[bnc + j][bk0 + 16] = k1s[j];
                BsV[bnc + j][bk0]      = v0s[j];
                BsV[bnc + j][bk0 + 16] = v1s[j];
            }
        }
        __syncthreads();

        bf16x8 af[4], bfK[4], bfV[4];
#pragma unroll
        for (int mi = 0; mi < 4; mi++)
            af[mi] = *(const bf16x8*)&As[wm * 64 + mi * 16 + lrow][quad * 8];
#pragma unroll
        for (int ni = 0; ni < 4; ni++) {
            bfK[ni] = *(const bf16x8*)&BsK[wn * 64 + ni * 16 + lrow][quad * 8];
            bfV[ni] = *(const bf16x8*)&BsV[wn * 64 + ni * 16 + lrow][quad * 8];
        }
#pragma unroll
        for (int mi = 0; mi < 4; mi++)
#pragma unroll
            for (int ni = 0; ni < 4; ni++) {
                accK[mi][ni] = __builtin_amdgcn_mfma_f32_16x16x32_bf16(
                    af[mi], bfK[ni], accK[mi][ni], 0, 0, 0);
                accV[mi][ni] = __builtin_amdgcn_mfma_f32_16x16x32_bf16(
                    af[mi], bfV[ni], accV[mi][ni], 0, 0, 0);
            }
    }

#pragma unroll
    for (int ni = 0; ni < 4; ni++) {
        const int colw = n0 + wn * 64 + ni * 16 + lrow;
        const float bkf = bk[colw];
        const float bvf = bv[colw];
        float pKV = 0.f, pK = 0.f;
#pragma unroll
        for (int mi = 0; mi < 4; mi++) {
#pragma unroll
            for (int r = 0; r < 4; r++) {
                const float kk = accK[mi][ni][r] + bkf;
                const float K  = (kk > 0.f) ? (kk + 1.f) : __expf(kk);
                const float vv = accV[mi][ni][r] + bvf;
                pKV += K * vv;
                pK  += K;
            }
        }
        pKV += __shfl_xor(pKV, 16, 64);
        pKV += __shfl_xor(pKV, 32, 64);
        pK  += __shfl_xor(pK, 16, 64);
        pK  += __shfl_xor(pK, 32, 64);
        if (quad == 0) {
            atomicAdd(&KVZ[b * HD + colw].x, pKV);
            atomicAdd(&KVZ[b * HD + colw].y, pK);
        }
    }
}

// ---------- Kernel 2 (fused): gelu((KV/Ksum)@wo + bo) broadcast to out -----
__global__ __launch_bounds__(256)
void rowgemm_bcast(const float2* __restrict__ KVZ,
                   const float* __restrict__ wo, const float* __restrict__ bo,
                   float* __restrict__ out)
{
    __shared__ float a[1024];
    __shared__ float red[4][64];
    __shared__ float sval[64];
    const int t = threadIdx.x;
    const int b = blockIdx.x;
    const int o0 = blockIdx.y * 64;
    const int s0 = blockIdx.z * 512;

    for (int c = t; c < 1024; c += 256) {
        const float2 z = KVZ[b * HD + c];
        a[c] = z.x / z.y;
    }
    __syncthreads();

    const int cs = t >> 6, oi = t & 63;
    float p = 0.f;
    const int cbeg = cs * 256;
    for (int c = cbeg; c < cbeg + 256; ++c)
        p += a[c] * wo[(size_t)c * HD + o0 + oi];
    red[cs][oi] = p;
    __syncthreads();

    if (t < 64) {
        float v = red[0][t] + red[1][t] + red[2][t] + red[3][t] + bo[o0 + t];
        sval[t] = 0.5f * v *
            (1.f + tanhf(0.7978845608028654f * (v + 0.044715f * v * v * v)));
    }
    __syncthreads();

    const float4 sv4 = *(const float4*)&sval[(t & 15) * 4];
    for (int r = t >> 4; r < 512; r += 16)
        *(float4*)&out[((size_t)(b * SEQ + s0 + r)) * HD + o0 + (t & 15) * 4] = sv4;
}

// ---------- Fallback epilogue kernels ----------
__global__ __launch_bounds__(256)
void rowgemm(const float2* __restrict__ KVZ,
             const float* __restrict__ wo, const float* __restrict__ bo,
             float* __restrict__ rowf)
{
    __shared__ float a[1024];
    __shared__ float red[4][64];
    const int t = threadIdx.x;
    const int b = blockIdx.x;
    const int o0 = blockIdx.y * 64;

    for (int c = t; c < 1024; c += 256) {
        const float2 z = KVZ[b * HD + c];
        a[c] = z.x / z.y;
    }
    __syncthreads();

    const int cs = t >> 6, oi = t & 63;
    float p = 0.f;
    const int cbeg = cs * 256;
    for (int c = cbeg; c < cbeg + 256; ++c)
        p += a[c] * wo[(size_t)c * HD + o0 + oi];
    red[cs][oi] = p;
    __syncthreads();

    if (t < 64) {
        float v = red[0][t] + red[1][t] + red[2][t] + red[3][t] + bo[o0 + t];
        const float g = 0.5f * v *
            (1.f + tanhf(0.7978845608028654f * (v + 0.044715f * v * v * v)));
        rowf[b * HD + o0 + t] = g;
    }
}

__global__ __launch_bounds__(256)
void broadcast_rows(const float* __restrict__ rowf, float* __restrict__ out)
{
    const size_t idx = (size_t)blockIdx.x * 256 + threadIdx.x;
    const size_t p = idx * 4;
    const int row = (int)(p >> 10);
    const int b = row >> 12;
    const int col = (int)(p & 1023);
    *(float4*)(out + p) = *(const float4*)(rowf + b * HD + col);
}

extern "C" void kernel_launch(void* const* d_in, const int* in_sizes, int n_in,
                              void* d_out, int out_size, void* d_ws, size_t ws_size,
                              hipStream_t stream)
{
    const float* x  = (const float*)d_in[0];
    const float* wk = (const float*)d_in[3];
    const float* bk = (const float*)d_in[4];
    const float* wv = (const float*)d_in[5];
    const float* bv = (const float*)d_in[6];
    const float* wo = (const float*)d_in[7];
    const float* bo = (const float*)d_in[8];
    float* out = (float*)d_out;

    const size_t NEED = (size_t)72 * 1024 * 1024;
    if (ws_size >= NEED) {
        unsigned short* xb  = (unsigned short*)d_ws;                       // 64 MiB
        unsigned short* wkT = (unsigned short*)((char*)d_ws + (67u << 20));// 2 MiB
        unsigned short* wvT = (unsigned short*)((char*)d_ws + (69u << 20));// 2 MiB
        float2* KVZ = (float2*)((char*)d_ws + (71u << 20));                // 64 KiB

        prep<<<dim3(16384 + 512 + 1), 256, 0, stream>>>(x, xb, wk, wv, wkT, wvT,
                                                        (float4*)KVZ);
        kv_gemm_fast<<<dim3(1024), 512, 0, stream>>>(xb, wkT, wvT, bk, bv, KVZ);
        rowgemm_bcast<<<dim3(8, 16, 8), 256, 0, stream>>>(KVZ, wo, bo, out);
    } else {
        float2* KVZ = (float2*)d_ws;
        float* rowf = (float*)((char*)d_ws + 65536);
        hipMemsetAsync(KVZ, 0, 8 * HD * sizeof(float2), stream);
        kv_gemm<<<dim3(8, 256), 256, 0, stream>>>(x, wk, bk, wv, bv, KVZ);
        rowgemm<<<dim3(8, 16), 256, 0, stream>>>(KVZ, wo, bo, rowf);
        broadcast_rows<<<dim3((MROWS * HD / 4) / 256), 256, 0, stream>>>(rowf, out);
    }
}